// Round 3
// baseline (1823.504 us; speedup 1.0000x reference)
//
#include <hip/hip_runtime.h>
#include <hip/hip_bf16.h>

#define NC 100000
#define NPC 10000
#define NE 1000000
#define DD 128
#define NLAYER 3
#define DSQ (DD*DD)

// ---- fold the two self-matrices and the two neighbor biases (all f32) ----
__global__ void k_prep(const float* __restrict__ Ws, const float* __restrict__ bn,
                       float* __restrict__ Wsum, float* __restrict__ bsum)
{
  int i = blockIdx.x*blockDim.x + threadIdx.x;
  if (i >= NLAYER*DSQ) return;
  int l = i / DSQ, e = i % DSQ;
  Wsum[i] = Ws[(size_t)l*2*DSQ + e] + Ws[(size_t)l*2*DSQ + DSQ + e];
  if (e < DD) bsum[l*DD+e] = bn[l*2*DD+e] + bn[l*2*DD+DD+e];
}

// ---- CSR build ----
__global__ void k_count(const int* __restrict__ dst, int* __restrict__ deg){
  int e = blockIdx.x*blockDim.x + threadIdx.x;
  if (e < NE) atomicAdd(&deg[dst[e]], 1);
}

__global__ void k_scan1(const int* __restrict__ deg, int* __restrict__ rowptr,
                        int* __restrict__ partials){
  __shared__ int s[1024];
  int b = blockIdx.x, t = threadIdx.x, i = b*1024 + t;
  int x = (i < NC) ? deg[i] : 0;
  s[t] = x; __syncthreads();
  for (int off = 1; off < 1024; off <<= 1){
    int v = (t >= off) ? s[t-off] : 0;
    __syncthreads();
    s[t] += v;
    __syncthreads();
  }
  if (i < NC) rowptr[i] = s[t] - x;   // exclusive within block
  if (t == 1023) partials[b] = s[t];  // block total
}

__global__ void k_scan2(int* __restrict__ partials, int n){
  __shared__ int s[128];
  int t = threadIdx.x;
  s[t] = (t < n) ? partials[t] : 0;
  __syncthreads();
  if (t == 0){
    int acc = 0;
    for (int j = 0; j < n; ++j){ int v = s[j]; s[j] = acc; acc += v; }
  }
  __syncthreads();
  if (t < n) partials[t] = s[t];
}

__global__ void k_finalize(int* __restrict__ rowptr, const int* __restrict__ partials,
                           int* __restrict__ cursor){
  int i = blockIdx.x*blockDim.x + threadIdx.x;
  if (i >= NC) return;
  int r = rowptr[i] + partials[i >> 10];
  rowptr[i] = r;
  cursor[i] = r;
  if (i == 0) rowptr[NC] = NE;
}

__global__ void k_fill(const int* __restrict__ src, const int* __restrict__ dst,
                       int* __restrict__ cursor, int* __restrict__ eidx){
  int e = blockIdx.x*blockDim.x + threadIdx.x;
  if (e < NE){
    int p = atomicAdd(&cursor[dst[e]], 1);
    eidx[p] = src[e];
  }
}

// ---- fused layer: [neighbor-mean aggregation] + (1|3)-matrix GEMM + bias + LN (+ReLU) ----
// Block: 256 threads, 32 rows. Wave w owns rows w*8..w*8+7 for cols (lane, lane+64).
// A-tiles live in LDS transposed [k][row]; compute reads are wave-uniform broadcasts.
// All f32. Blocks only write their own 32 rows -> in-place (out==A0) is safe.
template<int NMAT, bool RELU>
__global__ void __launch_bounds__(256) k_layer(
    const float* __restrict__ A0,        // [M,128] self input
    const float* __restrict__ hin,       // [NC,128] h for aggregation (NMAT==3)
    const int* __restrict__ rp0, const int* __restrict__ ei0,
    const int* __restrict__ rp1, const int* __restrict__ ei1,
    const float* __restrict__ W0, const float* __restrict__ W1, const float* __restrict__ W2,
    const float* __restrict__ bias, const float* __restrict__ gamma, const float* __restrict__ beta,
    float* __restrict__ out, int M)
{
  __shared__ float aS[NMAT][DD][36];   // pad 36 keeps float4 rows 16B-aligned
  const int t = threadIdx.x;
  const int row0 = blockIdx.x * 32;
  const int wv = t >> 6, lane = t & 63;

  // stage self rows (f32, transposed [k][row])
  #pragma unroll
  for (int p = 0; p < 4; ++p){
    int f = t + p*256;
    int r = f >> 5, k4 = (f & 31) << 2;
    float4 v = make_float4(0.f,0.f,0.f,0.f);
    if (row0 + r < M) v = *(const float4*)(A0 + (size_t)(row0+r)*DD + k4);
    aS[0][k4+0][r] = v.x; aS[0][k4+1][r] = v.y;
    aS[0][k4+2][r] = v.z; aS[0][k4+3][r] = v.w;
  }

  // fused neighbor-mean aggregation: wave-uniform edge row -> coalesced 512B reads
  if constexpr (NMAT == 3){
    const float* hb = hin + lane*2;      // this lane's 2 columns
    #pragma unroll
    for (int rel = 0; rel < 2; ++rel){
      const int* __restrict__ rp = rel ? rp1 : rp0;
      const int* __restrict__ ei = rel ? ei1 : ei0;
      for (int r = 0; r < 8; ++r){
        const int row = row0 + wv*8 + r;
        const int beg = rp[row], end = rp[row+1];
        float a0 = 0.f, a1 = 0.f;
        int e = beg;
        for (; e + 4 <= end; e += 4){    // 4-deep ILP on the gather chain
          int s0 = ei[e], s1 = ei[e+1], s2 = ei[e+2], s3 = ei[e+3];
          float2 v0 = *(const float2*)(hb + (size_t)s0*DD);
          float2 v1 = *(const float2*)(hb + (size_t)s1*DD);
          float2 v2 = *(const float2*)(hb + (size_t)s2*DD);
          float2 v3 = *(const float2*)(hb + (size_t)s3*DD);
          a0 += v0.x + v1.x + v2.x + v3.x;
          a1 += v0.y + v1.y + v2.y + v3.y;
        }
        for (; e < end; ++e){
          float2 v = *(const float2*)(hb + (size_t)ei[e]*DD);
          a0 += v.x; a1 += v.y;
        }
        const int d = end - beg;
        const float iv = 1.0f / (float)(d > 1 ? d : 1);
        aS[1+rel][lane*2  ][wv*8+r] = a0 * iv;
        aS[1+rel][lane*2+1][wv*8+r] = a1 * iv;
      }
    }
  }
  __syncthreads();

  const int j0 = lane;
  const int r0 = wv << 3;
  float acc[8][2];
  #pragma unroll
  for (int r = 0; r < 8; ++r){ acc[r][0] = 0.f; acc[r][1] = 0.f; }

  #pragma unroll 2
  for (int k = 0; k < DD; ++k){
    {
      float4 aA = *(const float4*)&aS[0][k][r0];
      float4 aB = *(const float4*)&aS[0][k][r0+4];
      float a[8] = {aA.x,aA.y,aA.z,aA.w,aB.x,aB.y,aB.z,aB.w};
      float w0 = W0[k*DD + j0], w1 = W0[k*DD + j0 + 64];
      #pragma unroll
      for (int r = 0; r < 8; ++r){
        acc[r][0] = fmaf(a[r], w0, acc[r][0]);
        acc[r][1] = fmaf(a[r], w1, acc[r][1]);
      }
    }
    if constexpr (NMAT == 3){
      {
        float4 aA = *(const float4*)&aS[1][k][r0];
        float4 aB = *(const float4*)&aS[1][k][r0+4];
        float a[8] = {aA.x,aA.y,aA.z,aA.w,aB.x,aB.y,aB.z,aB.w};
        float w0 = W1[k*DD + j0], w1 = W1[k*DD + j0 + 64];
        #pragma unroll
        for (int r = 0; r < 8; ++r){
          acc[r][0] = fmaf(a[r], w0, acc[r][0]);
          acc[r][1] = fmaf(a[r], w1, acc[r][1]);
        }
      }
      {
        float4 aA = *(const float4*)&aS[2][k][r0];
        float4 aB = *(const float4*)&aS[2][k][r0+4];
        float a[8] = {aA.x,aA.y,aA.z,aA.w,aB.x,aB.y,aB.z,aB.w};
        float w0 = W2[k*DD + j0], w1 = W2[k*DD + j0 + 64];
        #pragma unroll
        for (int r = 0; r < 8; ++r){
          acc[r][0] = fmaf(a[r], w0, acc[r][0]);
          acc[r][1] = fmaf(a[r], w1, acc[r][1]);
        }
      }
    }
  }

  // epilogue: bias + LayerNorm (+ReLU), wave-level row reduction over 64 lanes x 2 cols
  float bj0 = bias[j0], bj1 = bias[j0+64];
  float g0 = gamma[j0], g1 = gamma[j0+64];
  float be0 = beta[j0], be1 = beta[j0+64];
  #pragma unroll
  for (int r = 0; r < 8; ++r){
    float v0 = acc[r][0] + bj0;
    float v1 = acc[r][1] + bj1;
    float s = v0 + v1;
    #pragma unroll
    for (int m = 32; m > 0; m >>= 1) s += __shfl_xor(s, m);
    float mu = s * (1.0f/128.0f);
    float d0 = v0 - mu, d1 = v1 - mu;
    float q = d0*d0 + d1*d1;
    #pragma unroll
    for (int m = 32; m > 0; m >>= 1) q += __shfl_xor(q, m);
    float rs = rsqrtf(q * (1.0f/128.0f) + 1e-5f);
    float y0 = fmaf(d0*rs, g0, be0);
    float y1 = fmaf(d1*rs, g1, be1);
    if (RELU){ y0 = fmaxf(y0, 0.f); y1 = fmaxf(y1, 0.f); }
    int row = row0 + r0 + r;
    if (row < M){
      out[(size_t)row*DD + j0]      = y0;
      out[(size_t)row*DD + j0 + 64] = y1;
    }
  }
}

extern "C" void kernel_launch(void* const* d_in, const int* in_sizes, int n_in,
                              void* d_out, int out_size, void* d_ws, size_t ws_size,
                              hipStream_t stream)
{
  const float* x_c    = (const float*)d_in[0];
  const float* x_pc   = (const float*)d_in[1];
  const int*   src0   = (const int*)d_in[2];
  const int*   dst0   = (const int*)d_in[3];
  const int*   src1   = (const int*)d_in[4];
  const int*   dst1   = (const int*)d_in[5];
  const float* W_self = (const float*)d_in[6];
  const float* W_nei  = (const float*)d_in[7];
  const float* b_nei  = (const float*)d_in[8];
  const float* lin_W  = (const float*)d_in[9];
  const float* lin_b  = (const float*)d_in[10];
  const float* ln_g   = (const float*)d_in[11];
  const float* ln_b   = (const float*)d_in[12];
  (void)in_sizes; (void)n_in; (void)out_size; (void)ws_size;

  char* ws = (char*)d_ws;
  size_t off = 0;
  auto take = [&](size_t bytes)->char*{
    char* p = ws + off; off += (bytes + 255) & ~(size_t)255; return p;
  };
  float* hA    = (float*)take((size_t)NC*DD*4);       // 51.2 MB ping buffer
  float* Wsum  = (float*)take((size_t)NLAYER*DSQ*4);  //  0.2 MB
  float* bsum  = (float*)take((size_t)NLAYER*DD*4);
  int* rowptr0 = (int*)  take((size_t)(NC+1)*4);
  int* rowptr1 = (int*)  take((size_t)(NC+1)*4);
  int* cursor0 = (int*)  take((size_t)NC*4);
  int* cursor1 = (int*)  take((size_t)NC*4);
  int* eidx0   = (int*)  take((size_t)NE*4);          //  4.0 MB
  int* eidx1   = (int*)  take((size_t)NE*4);          //  4.0 MB
  int* part0   = (int*)  take(128*4);
  int* part1   = (int*)  take(128*4);                 // total ~ 61 MB

  float* out_pc = (float*)d_out;                      // [NPC,128] f32 (in-place pc buffer)
  float* out_h  = (float*)d_out + (size_t)NPC*DD;     // [NC,128]  f32 (pong buffer = final h)

  // weight folding
  k_prep<<<(NLAYER*DSQ + 255)/256, 256, 0, stream>>>(W_self, b_nei, Wsum, bsum);

  // CSR build (graph is layer-invariant)
  hipMemsetAsync(cursor0, 0, (size_t)NC*4, stream);
  hipMemsetAsync(cursor1, 0, (size_t)NC*4, stream);
  k_count<<<(NE + 255)/256, 256, 0, stream>>>(dst0, cursor0);
  k_count<<<(NE + 255)/256, 256, 0, stream>>>(dst1, cursor1);
  const int SB = (NC + 1023)/1024;  // 98
  k_scan1<<<SB, 1024, 0, stream>>>(cursor0, rowptr0, part0);
  k_scan1<<<SB, 1024, 0, stream>>>(cursor1, rowptr1, part1);
  k_scan2<<<1, 128, 0, stream>>>(part0, SB);
  k_scan2<<<1, 128, 0, stream>>>(part1, SB);
  k_finalize<<<(NC + 255)/256, 256, 0, stream>>>(rowptr0, part0, cursor0);
  k_finalize<<<(NC + 255)/256, 256, 0, stream>>>(rowptr1, part1, cursor1);
  k_fill<<<(NE + 255)/256, 256, 0, stream>>>(src0, dst0, cursor0, eidx0);
  k_fill<<<(NE + 255)/256, 256, 0, stream>>>(src1, dst1, cursor1, eidx1);

  const int GB = NC/32;            // 3125
  const int PB = (NPC + 31)/32;    // 313

  // layer 0: h: x_c -> out_h ; pc: x_pc -> out_pc
  k_layer<3,true><<<GB, 256, 0, stream>>>(
      x_c, x_c, rowptr0, eidx0, rowptr1, eidx1,
      Wsum, W_nei, W_nei + DSQ, bsum, ln_g, ln_b, out_h, NC);
  k_layer<1,true><<<PB, 256, 0, stream>>>(
      x_pc, nullptr, nullptr, nullptr, nullptr, nullptr,
      lin_W, nullptr, nullptr, lin_b, ln_g, ln_b, out_pc, NPC);

  // layer 1: h: out_h -> hA ; pc in place
  k_layer<3,true><<<GB, 256, 0, stream>>>(
      out_h, out_h, rowptr0, eidx0, rowptr1, eidx1,
      Wsum + DSQ, W_nei + 2*DSQ, W_nei + 3*DSQ, bsum + DD,
      ln_g + DD, ln_b + DD, hA, NC);
  k_layer<1,true><<<PB, 256, 0, stream>>>(
      out_pc, nullptr, nullptr, nullptr, nullptr, nullptr,
      lin_W + DSQ, nullptr, nullptr, lin_b + DD, ln_g + DD, ln_b + DD, out_pc, NPC);

  // layer 2 (final, no ReLU): h: hA -> out_h ; pc in place (final)
  k_layer<3,false><<<GB, 256, 0, stream>>>(
      hA, hA, rowptr0, eidx0, rowptr1, eidx1,
      Wsum + 2*DSQ, W_nei + 4*DSQ, W_nei + 5*DSQ, bsum + 2*DD,
      ln_g + 2*DD, ln_b + 2*DD, out_h, NC);
  k_layer<1,false><<<PB, 256, 0, stream>>>(
      out_pc, nullptr, nullptr, nullptr, nullptr, nullptr,
      lin_W + 2*DSQ, nullptr, nullptr, lin_b + 2*DD, ln_g + 2*DD, ln_b + 2*DD, out_pc, NPC);
}

// Round 4
// 1270.740 us; speedup vs baseline: 1.4350x; 1.4350x over previous
//
#include <hip/hip_runtime.h>
#include <hip/hip_bf16.h>

typedef __hip_bfloat16 bf16;

#define NC 100000
#define NPC 10000
#define NE 1000000
#define DD 128
#define NLAYER 3
#define DSQ (DD*DD)

__device__ __forceinline__ bf16 f2b(float v){ return __float2bfloat16(v); }
__device__ __forceinline__ void unpack2(unsigned u, float& a, float& b){
  a = __uint_as_float(u << 16);
  b = __uint_as_float(u & 0xffff0000u);
}
__device__ __forceinline__ unsigned pack2(float a, float b){
  return (unsigned)__bfloat16_as_ushort(f2b(a)) |
         ((unsigned)__bfloat16_as_ushort(f2b(b)) << 16);
}
// LDS bank swizzle: XOR row index with k-bits 3..5 (keeps 16B alignment of float4)
__device__ __forceinline__ int SWZ(int k, int r){ return r ^ (((k >> 3) & 7) << 2); }

// ---- fold the two self-matrices and the two neighbor biases (all f32) ----
__global__ void k_prep(const float* __restrict__ Ws, const float* __restrict__ bn,
                       float* __restrict__ Wsum, float* __restrict__ bsum)
{
  int i = blockIdx.x*blockDim.x + threadIdx.x;
  if (i >= NLAYER*DSQ) return;
  int l = i / DSQ, e = i % DSQ;
  Wsum[i] = Ws[(size_t)l*2*DSQ + e] + Ws[(size_t)l*2*DSQ + DSQ + e];
  if (e < DD) bsum[l*DD+e] = bn[l*2*DD+e] + bn[l*2*DD+DD+e];
}

// ---- f32 -> bf16 mirror cast, 8 elems/thread ----
__global__ void k_f2b(const float* __restrict__ in, ushort* __restrict__ out, int n){
  int i = (blockIdx.x*blockDim.x + threadIdx.x) * 8;
  if (i >= n) return;
  float4 a = *(const float4*)(in + i);
  float4 b = *(const float4*)(in + i + 4);
  uint4 o;
  o.x = pack2(a.x, a.y); o.y = pack2(a.z, a.w);
  o.z = pack2(b.x, b.y); o.w = pack2(b.z, b.w);
  *(uint4*)(out + i) = o;
}

// ---- CSR build (both relations via blockIdx.y) ----
__global__ void k_count(const int* __restrict__ dst0, const int* __restrict__ dst1,
                        int* __restrict__ deg0, int* __restrict__ deg1){
  int e = blockIdx.x*blockDim.x + threadIdx.x;
  if (e >= NE) return;
  if (blockIdx.y) atomicAdd(&deg1[dst1[e]], 1);
  else            atomicAdd(&deg0[dst0[e]], 1);
}

__global__ void k_scan1(const int* __restrict__ deg, int* __restrict__ rowptr,
                        int* __restrict__ partials){
  __shared__ int s[1024];
  int b = blockIdx.x, t = threadIdx.x, i = b*1024 + t;
  int x = (i < NC) ? deg[i] : 0;
  s[t] = x; __syncthreads();
  for (int off = 1; off < 1024; off <<= 1){
    int v = (t >= off) ? s[t-off] : 0;
    __syncthreads();
    s[t] += v;
    __syncthreads();
  }
  if (i < NC) rowptr[i] = s[t] - x;   // exclusive within block
  if (t == 1023) partials[b] = s[t];  // block total
}

__global__ void k_scan2(int* __restrict__ partials, int n){
  __shared__ int s[128];
  int t = threadIdx.x;
  s[t] = (t < n) ? partials[t] : 0;
  __syncthreads();
  if (t == 0){
    int acc = 0;
    for (int j = 0; j < n; ++j){ int v = s[j]; s[j] = acc; acc += v; }
  }
  __syncthreads();
  if (t < n) partials[t] = s[t];
}

__global__ void k_finalize(int* __restrict__ rowptr, const int* __restrict__ partials,
                           int* __restrict__ cursor){
  int i = blockIdx.x*blockDim.x + threadIdx.x;
  if (i >= NC) return;
  int r = rowptr[i] + partials[i >> 10];
  rowptr[i] = r;
  cursor[i] = r;
  if (i == 0) rowptr[NC] = NE;
}

__global__ void k_fill(const int* __restrict__ src0, const int* __restrict__ dst0,
                       const int* __restrict__ src1, const int* __restrict__ dst1,
                       int* __restrict__ cur0, int* __restrict__ cur1,
                       int* __restrict__ ei0, int* __restrict__ ei1){
  int e = blockIdx.x*blockDim.x + threadIdx.x;
  if (e >= NE) return;
  if (blockIdx.y){ int p = atomicAdd(&cur1[dst1[e]], 1); ei1[p] = src1[e]; }
  else           { int p = atomicAdd(&cur0[dst0[e]], 1); ei0[p] = src0[e]; }
}

// ---- neighbor-mean aggregation: one wave per node, both relations via blockIdx.y ----
// No LDS, low VGPR -> high occupancy hides the random-gather latency.
// bf16 h rows (256B), lane reads one uint = cols {2*lane, 2*lane+1}.
__global__ void __launch_bounds__(256) k_agg(
    const ushort* __restrict__ h16,
    const int* __restrict__ rp0, const int* __restrict__ ei0,
    const int* __restrict__ rp1, const int* __restrict__ ei1,
    uint* __restrict__ m0, uint* __restrict__ m1)
{
  const int node = blockIdx.x*4 + (threadIdx.x >> 6);
  const int lane = threadIdx.x & 63;
  const int rel  = blockIdx.y;
  const int* __restrict__ rp = rel ? rp1 : rp0;
  const int* __restrict__ ei = rel ? ei1 : ei0;
  const uint* __restrict__ hu = (const uint*)h16 + lane;   // row stride = 64 uints
  const int beg = rp[node], end = rp[node+1];
  float a0 = 0.f, a1 = 0.f;
  int e = beg;
  for (; e + 4 <= end; e += 4){
    int s0 = ei[e], s1 = ei[e+1], s2 = ei[e+2], s3 = ei[e+3];
    uint u0 = hu[(size_t)s0 << 6];
    uint u1 = hu[(size_t)s1 << 6];
    uint u2 = hu[(size_t)s2 << 6];
    uint u3 = hu[(size_t)s3 << 6];
    float f0, f1;
    unpack2(u0,f0,f1); a0 += f0; a1 += f1;
    unpack2(u1,f0,f1); a0 += f0; a1 += f1;
    unpack2(u2,f0,f1); a0 += f0; a1 += f1;
    unpack2(u3,f0,f1); a0 += f0; a1 += f1;
  }
  for (; e < end; ++e){
    float f0, f1; unpack2(hu[(size_t)ei[e] << 6], f0, f1);
    a0 += f0; a1 += f1;
  }
  const int d = end - beg;
  const float iv = 1.0f / (float)(d > 1 ? d : 1);
  (rel ? m1 : m0)[(size_t)node*64 + lane] = pack2(a0*iv, a1*iv);
}

// ---- fused (1|3)-matrix GEMM + bias + LayerNorm (+ReLU) ----
// Block: 256 threads, 32 rows. Wave w owns rows w*8..w*8+7 for cols (lane, lane+64).
// A-tiles in LDS transposed [k][row], XOR-swizzled; compute reads are wave-uniform.
// Row-local -> in-place (out==A0) is safe. Optionally writes bf16 mirror of out.
template<int NMAT, bool RELU, bool MIRROR>
__global__ void __launch_bounds__(256) k_layer(
    const float* __restrict__ A0,        // [M,128] self input (f32)
    const uint* __restrict__ M0,         // [M,64] bf16-pair mean (rel 0)
    const uint* __restrict__ M1,         // [M,64] bf16-pair mean (rel 1)
    const float* __restrict__ W0, const float* __restrict__ W1, const float* __restrict__ W2,
    const float* __restrict__ bias, const float* __restrict__ gamma, const float* __restrict__ beta,
    float* __restrict__ out, ushort* __restrict__ mirror, int M)
{
  __shared__ float aS[NMAT][DD][32];
  const int t = threadIdx.x;
  const int row0 = blockIdx.x * 32;
  const int wv = t >> 6, lane = t & 63;

  // stage self rows (f32 -> [k][row], swizzled)
  #pragma unroll
  for (int p = 0; p < 4; ++p){
    int f = t + p*256;
    int r = f >> 5, k4 = (f & 31) << 2;
    float4 v = make_float4(0.f,0.f,0.f,0.f);
    if (row0 + r < M) v = *(const float4*)(A0 + (size_t)(row0+r)*DD + k4);
    aS[0][k4+0][SWZ(k4+0,r)] = v.x; aS[0][k4+1][SWZ(k4+1,r)] = v.y;
    aS[0][k4+2][SWZ(k4+2,r)] = v.z; aS[0][k4+3][SWZ(k4+3,r)] = v.w;
  }
  // stage means (bf16 -> f32, swizzled)
  if constexpr (NMAT == 3){
    #pragma unroll
    for (int m = 1; m < 3; ++m){
      const uint* Mm = (m == 1) ? M0 : M1;
      #pragma unroll
      for (int p = 0; p < 2; ++p){
        int f = t + p*256;
        int r = f >> 4, k8 = (f & 15) << 3;
        uint4 v = make_uint4(0u,0u,0u,0u);
        if (row0 + r < M) v = *(const uint4*)(Mm + (size_t)(row0+r)*64 + (k8 >> 1));
        float x, y;
        unpack2(v.x,x,y); aS[m][k8+0][SWZ(k8+0,r)]=x; aS[m][k8+1][SWZ(k8+1,r)]=y;
        unpack2(v.y,x,y); aS[m][k8+2][SWZ(k8+2,r)]=x; aS[m][k8+3][SWZ(k8+3,r)]=y;
        unpack2(v.z,x,y); aS[m][k8+4][SWZ(k8+4,r)]=x; aS[m][k8+5][SWZ(k8+5,r)]=y;
        unpack2(v.w,x,y); aS[m][k8+6][SWZ(k8+6,r)]=x; aS[m][k8+7][SWZ(k8+7,r)]=y;
      }
    }
  }
  __syncthreads();

  const int j0 = lane;
  const int r0 = wv << 3;
  float acc[8][2];
  #pragma unroll
  for (int r = 0; r < 8; ++r){ acc[r][0] = 0.f; acc[r][1] = 0.f; }

  #pragma unroll 2
  for (int k = 0; k < DD; ++k){
    const int rA = SWZ(k, r0), rB = SWZ(k, r0+4);
    {
      float4 aA = *(const float4*)&aS[0][k][rA];
      float4 aB = *(const float4*)&aS[0][k][rB];
      float a[8] = {aA.x,aA.y,aA.z,aA.w,aB.x,aB.y,aB.z,aB.w};
      float w0 = W0[k*DD + j0], w1 = W0[k*DD + j0 + 64];
      #pragma unroll
      for (int r = 0; r < 8; ++r){
        acc[r][0] = fmaf(a[r], w0, acc[r][0]);
        acc[r][1] = fmaf(a[r], w1, acc[r][1]);
      }
    }
    if constexpr (NMAT == 3){
      {
        float4 aA = *(const float4*)&aS[1][k][rA];
        float4 aB = *(const float4*)&aS[1][k][rB];
        float a[8] = {aA.x,aA.y,aA.z,aA.w,aB.x,aB.y,aB.z,aB.w};
        float w0 = W1[k*DD + j0], w1 = W1[k*DD + j0 + 64];
        #pragma unroll
        for (int r = 0; r < 8; ++r){
          acc[r][0] = fmaf(a[r], w0, acc[r][0]);
          acc[r][1] = fmaf(a[r], w1, acc[r][1]);
        }
      }
      {
        float4 aA = *(const float4*)&aS[2][k][rA];
        float4 aB = *(const float4*)&aS[2][k][rB];
        float a[8] = {aA.x,aA.y,aA.z,aA.w,aB.x,aB.y,aB.z,aB.w};
        float w0 = W2[k*DD + j0], w1 = W2[k*DD + j0 + 64];
        #pragma unroll
        for (int r = 0; r < 8; ++r){
          acc[r][0] = fmaf(a[r], w0, acc[r][0]);
          acc[r][1] = fmaf(a[r], w1, acc[r][1]);
        }
      }
    }
  }

  // epilogue: bias + LayerNorm (+ReLU), wave-level row reduction over 64 lanes x 2 cols
  float bj0 = bias[j0], bj1 = bias[j0+64];
  float g0 = gamma[j0], g1 = gamma[j0+64];
  float be0 = beta[j0], be1 = beta[j0+64];
  #pragma unroll
  for (int r = 0; r < 8; ++r){
    float v0 = acc[r][0] + bj0;
    float v1 = acc[r][1] + bj1;
    float s = v0 + v1;
    #pragma unroll
    for (int m = 32; m > 0; m >>= 1) s += __shfl_xor(s, m);
    float mu = s * (1.0f/128.0f);
    float d0 = v0 - mu, d1 = v1 - mu;
    float q = d0*d0 + d1*d1;
    #pragma unroll
    for (int m = 32; m > 0; m >>= 1) q += __shfl_xor(q, m);
    float rs = rsqrtf(q * (1.0f/128.0f) + 1e-5f);
    float y0 = fmaf(d0*rs, g0, be0);
    float y1 = fmaf(d1*rs, g1, be1);
    if (RELU){ y0 = fmaxf(y0, 0.f); y1 = fmaxf(y1, 0.f); }
    int row = row0 + r0 + r;
    if (row < M){
      out[(size_t)row*DD + j0]      = y0;
      out[(size_t)row*DD + j0 + 64] = y1;
      if (MIRROR){
        mirror[(size_t)row*DD + j0]      = __bfloat16_as_ushort(f2b(y0));
        mirror[(size_t)row*DD + j0 + 64] = __bfloat16_as_ushort(f2b(y1));
      }
    }
  }
}

extern "C" void kernel_launch(void* const* d_in, const int* in_sizes, int n_in,
                              void* d_out, int out_size, void* d_ws, size_t ws_size,
                              hipStream_t stream)
{
  const float* x_c    = (const float*)d_in[0];
  const float* x_pc   = (const float*)d_in[1];
  const int*   src0   = (const int*)d_in[2];
  const int*   dst0   = (const int*)d_in[3];
  const int*   src1   = (const int*)d_in[4];
  const int*   dst1   = (const int*)d_in[5];
  const float* W_self = (const float*)d_in[6];
  const float* W_nei  = (const float*)d_in[7];
  const float* b_nei  = (const float*)d_in[8];
  const float* lin_W  = (const float*)d_in[9];
  const float* lin_b  = (const float*)d_in[10];
  const float* ln_g   = (const float*)d_in[11];
  const float* ln_b   = (const float*)d_in[12];
  (void)in_sizes; (void)n_in; (void)out_size; (void)ws_size;

  char* ws = (char*)d_ws;
  size_t off = 0;
  auto take = [&](size_t bytes)->char*{
    char* p = ws + off; off += (bytes + 255) & ~(size_t)255; return p;
  };
  ushort* h16  = (ushort*)take((size_t)NC*DD*2);      // 25.6 MB bf16 mirror of h
  uint*   m0   = (uint*)  take((size_t)NC*64*4);      // 25.6 MB bf16-pair means
  uint*   m1   = (uint*)  take((size_t)NC*64*4);      // 25.6 MB
  float*  Wsum = (float*) take((size_t)NLAYER*DSQ*4); //  0.2 MB
  float*  bsum = (float*) take((size_t)NLAYER*DD*4);
  int* rowptr0 = (int*)   take((size_t)(NC+1)*4);
  int* rowptr1 = (int*)   take((size_t)(NC+1)*4);
  int* cursor0 = (int*)   take((size_t)NC*4);
  int* cursor1 = (int*)   take((size_t)NC*4);
  int* eidx0   = (int*)   take((size_t)NE*4);         //  4.0 MB
  int* eidx1   = (int*)   take((size_t)NE*4);         //  4.0 MB
  int* part0   = (int*)   take(128*4);
  int* part1   = (int*)   take(128*4);                // total ~ 87 MB

  float* out_pc = (float*)d_out;                      // [NPC,128] f32, updated in place
  float* out_h  = (float*)d_out + (size_t)NPC*DD;     // [NC,128]  f32 h, updated in place

  // weight folding + bf16 mirror of layer-0 h
  k_prep<<<(NLAYER*DSQ + 255)/256, 256, 0, stream>>>(W_self, b_nei, Wsum, bsum);
  k_f2b<<<(NC*DD/8 + 255)/256, 256, 0, stream>>>(x_c, h16, NC*DD);

  // CSR build (graph is layer-invariant)
  hipMemsetAsync(cursor0, 0, (size_t)NC*4, stream);
  hipMemsetAsync(cursor1, 0, (size_t)NC*4, stream);
  k_count<<<dim3((NE + 255)/256, 2), 256, 0, stream>>>(dst0, dst1, cursor0, cursor1);
  const int SB = (NC + 1023)/1024;  // 98
  k_scan1<<<SB, 1024, 0, stream>>>(cursor0, rowptr0, part0);
  k_scan1<<<SB, 1024, 0, stream>>>(cursor1, rowptr1, part1);
  k_scan2<<<1, 128, 0, stream>>>(part0, SB);
  k_scan2<<<1, 128, 0, stream>>>(part1, SB);
  k_finalize<<<(NC + 255)/256, 256, 0, stream>>>(rowptr0, part0, cursor0);
  k_finalize<<<(NC + 255)/256, 256, 0, stream>>>(rowptr1, part1, cursor1);
  k_fill<<<dim3((NE + 255)/256, 2), 256, 0, stream>>>(src0, dst0, src1, dst1,
                                                      cursor0, cursor1, eidx0, eidx1);

  const int GB = NC/32;            // 3125
  const int PB = (NPC + 31)/32;    // 313
  const dim3 AG(NC/4, 2);          // both relations

  // layer 0: h: x_c -> out_h (mirror h16) ; pc: x_pc -> out_pc
  k_agg<<<AG, 256, 0, stream>>>(h16, rowptr0, eidx0, rowptr1, eidx1, m0, m1);
  k_layer<3,true,true><<<GB, 256, 0, stream>>>(
      x_c, m0, m1, Wsum, W_nei, W_nei + DSQ, bsum, ln_g, ln_b, out_h, h16, NC);
  k_layer<1,true,false><<<PB, 256, 0, stream>>>(
      x_pc, nullptr, nullptr, lin_W, nullptr, nullptr,
      lin_b, ln_g, ln_b, out_pc, nullptr, NPC);

  // layer 1: h in place (mirror h16) ; pc in place
  k_agg<<<AG, 256, 0, stream>>>(h16, rowptr0, eidx0, rowptr1, eidx1, m0, m1);
  k_layer<3,true,true><<<GB, 256, 0, stream>>>(
      out_h, m0, m1, Wsum + DSQ, W_nei + 2*DSQ, W_nei + 3*DSQ, bsum + DD,
      ln_g + DD, ln_b + DD, out_h, h16, NC);
  k_layer<1,true,false><<<PB, 256, 0, stream>>>(
      out_pc, nullptr, nullptr, lin_W + DSQ, nullptr, nullptr,
      lin_b + DD, ln_g + DD, ln_b + DD, out_pc, nullptr, NPC);

  // layer 2 (final, no ReLU, no mirror): h in place ; pc in place
  k_agg<<<AG, 256, 0, stream>>>(h16, rowptr0, eidx0, rowptr1, eidx1, m0, m1);
  k_layer<3,false,false><<<GB, 256, 0, stream>>>(
      out_h, m0, m1, Wsum + 2*DSQ, W_nei + 4*DSQ, W_nei + 5*DSQ, bsum + 2*DD,
      ln_g + 2*DD, ln_b + 2*DD, out_h, nullptr, NC);
  k_layer<1,false,false><<<PB, 256, 0, stream>>>(
      out_pc, nullptr, nullptr, lin_W + 2*DSQ, nullptr, nullptr,
      lin_b + 2*DD, ln_g + 2*DD, ln_b + 2*DD, out_pc, nullptr, NPC);
}

// Round 5
// 867.177 us; speedup vs baseline: 2.1028x; 1.4654x over previous
//
#include <hip/hip_runtime.h>
#include <hip/hip_bf16.h>

typedef __hip_bfloat16 bf16;
typedef __attribute__((ext_vector_type(8))) short short8;
typedef __attribute__((ext_vector_type(4))) float f32x4;

#define NC 100000
#define NPC 10000
#define NE 1000000
#define DD 128
#define NLAYER 3
#define DSQ (DD*DD)
#define WPL 49152   // bf16 fragment elems per layer: 3 mats * 128 * 128

__device__ __forceinline__ bf16 f2b(float v){ return __float2bfloat16(v); }
__device__ __forceinline__ void unpack2(unsigned u, float& a, float& b){
  a = __uint_as_float(u << 16);
  b = __uint_as_float(u & 0xffff0000u);
}
__device__ __forceinline__ unsigned pack2(float a, float b){
  return (unsigned)__bfloat16_as_ushort(f2b(a)) |
         ((unsigned)__bfloat16_as_ushort(f2b(b)) << 16);
}
// LDS bank swizzle for the f32 pc kernel
__device__ __forceinline__ int SWZ(int k, int r){ return r ^ (((k >> 3) & 7) << 2); }

// ---- weights -> bf16, pre-swizzled into mfma_f32_16x16x32_bf16 B-fragment order ----
// frag = (mat*4 + kchunk)*8 + coltile ; within frag: lane = g*16 + (j&15), elem i
// holds B[k = 32*kchunk + 8*g + i][j = 16*coltile + (j&15)]
__global__ void k_prepw(const float* __restrict__ Ws, const float* __restrict__ Wn,
                        ushort* __restrict__ Bsw)
{
  int tid = blockIdx.x*256 + threadIdx.x;      // [l][mat][k][j]
  if (tid >= NLAYER*3*DSQ) return;
  int j = tid & 127, k = (tid >> 7) & 127;
  int lm = tid / DSQ, mat = lm % 3, l = lm / 3;
  float v;
  if (mat == 0) v = Ws[((size_t)l*2)*DSQ + k*DD + j] + Ws[((size_t)l*2+1)*DSQ + k*DD + j];
  else          v = Wn[((size_t)l*2 + (mat-1))*DSQ + k*DD + j];
  int tch = k >> 5, c = j >> 4, g = (k >> 3) & 3, i = k & 7, jj = j & 15;
  int frag = (mat*4 + tch)*8 + c;
  Bsw[(size_t)l*WPL + frag*512 + (g*16 + jj)*8 + i] = __bfloat16_as_ushort(f2b(v));
}

__global__ void k_prepb(const float* __restrict__ bn, float* __restrict__ bsum){
  int i = blockIdx.x*blockDim.x + threadIdx.x;
  if (i >= NLAYER*DD) return;
  int l = i / DD, e = i % DD;
  bsum[i] = bn[l*2*DD + e] + bn[l*2*DD + DD + e];
}

// ---- f32 -> bf16 mirror cast, 8 elems/thread ----
__global__ void k_f2b(const float* __restrict__ in, ushort* __restrict__ out, int n){
  int i = (blockIdx.x*blockDim.x + threadIdx.x) * 8;
  if (i >= n) return;
  float4 a = *(const float4*)(in + i);
  float4 b = *(const float4*)(in + i + 4);
  uint4 o;
  o.x = pack2(a.x, a.y); o.y = pack2(a.z, a.w);
  o.z = pack2(b.x, b.y); o.w = pack2(b.z, b.w);
  *(uint4*)(out + i) = o;
}

// ---- CSR build (both relations via blockIdx.y) ----
__global__ void k_count(const int* __restrict__ dst0, const int* __restrict__ dst1,
                        int* __restrict__ deg0, int* __restrict__ deg1){
  int e = blockIdx.x*blockDim.x + threadIdx.x;
  if (e >= NE) return;
  if (blockIdx.y) atomicAdd(&deg1[dst1[e]], 1);
  else            atomicAdd(&deg0[dst0[e]], 1);
}

__global__ void k_scan1(const int* __restrict__ deg, int* __restrict__ rowptr,
                        int* __restrict__ partials){
  __shared__ int s[1024];
  int b = blockIdx.x, t = threadIdx.x, i = b*1024 + t;
  int x = (i < NC) ? deg[i] : 0;
  s[t] = x; __syncthreads();
  for (int off = 1; off < 1024; off <<= 1){
    int v = (t >= off) ? s[t-off] : 0;
    __syncthreads();
    s[t] += v;
    __syncthreads();
  }
  if (i < NC) rowptr[i] = s[t] - x;
  if (t == 1023) partials[b] = s[t];
}

__global__ void k_scan2(int* __restrict__ partials, int n){
  __shared__ int s[128];
  int t = threadIdx.x;
  s[t] = (t < n) ? partials[t] : 0;
  __syncthreads();
  if (t == 0){
    int acc = 0;
    for (int j = 0; j < n; ++j){ int v = s[j]; s[j] = acc; acc += v; }
  }
  __syncthreads();
  if (t < n) partials[t] = s[t];
}

__global__ void k_finalize(int* __restrict__ rowptr, const int* __restrict__ partials,
                           int* __restrict__ cursor){
  int i = blockIdx.x*blockDim.x + threadIdx.x;
  if (i >= NC) return;
  int r = rowptr[i] + partials[i >> 10];
  rowptr[i] = r;
  cursor[i] = r;
  if (i == 0) rowptr[NC] = NE;
}

__global__ void k_fill(const int* __restrict__ src0, const int* __restrict__ dst0,
                       const int* __restrict__ src1, const int* __restrict__ dst1,
                       int* __restrict__ cur0, int* __restrict__ cur1,
                       int* __restrict__ ei0, int* __restrict__ ei1){
  int e = blockIdx.x*blockDim.x + threadIdx.x;
  if (e >= NE) return;
  if (blockIdx.y){ int p = atomicAdd(&cur1[dst1[e]], 1); ei1[p] = src1[e]; }
  else           { int p = atomicAdd(&cur0[dst0[e]], 1); ei0[p] = src0[e]; }
}

// ---- neighbor-mean aggregation: one wave per node, 2 edges per gather instr ----
// lane = half*32 + sl; each lane reads uint2 (8B) of row src[e+half] -> a wave
// instruction covers TWO 256B rows. eidx fetched 8-wide coalesced + shfl broadcast.
__global__ void __launch_bounds__(256) k_agg(
    const ushort* __restrict__ h16,
    const int* __restrict__ rp0, const int* __restrict__ ei0,
    const int* __restrict__ rp1, const int* __restrict__ ei1,
    uint2* __restrict__ m0, uint2* __restrict__ m1)
{
  const int node = blockIdx.x*4 + (threadIdx.x >> 6);
  const int lane = threadIdx.x & 63;
  const int half = lane >> 5, sl = lane & 31;
  const int* __restrict__ rp = blockIdx.y ? rp1 : rp0;
  const int* __restrict__ ei = blockIdx.y ? ei1 : ei0;
  const uint2* __restrict__ hu = (const uint2*)h16;   // 32 uint2 per row
  const int beg = rp[node], end = rp[node+1];
  float a0=0.f, a1=0.f, a2=0.f, a3=0.f;
  int e = beg;
  for (; e + 8 <= end; e += 8){
    int idx = ei[e + (lane & 7)];                     // one coalesced 32B load
    #pragma unroll
    for (int b = 0; b < 4; ++b){
      int row = __shfl(idx, 2*b + half);
      uint2 u = hu[(size_t)row*32 + sl];
      float f0,f1,f2,f3;
      unpack2(u.x,f0,f1); unpack2(u.y,f2,f3);
      a0 += f0; a1 += f1; a2 += f2; a3 += f3;
    }
  }
  for (; e + 2 <= end; e += 2){
    int ia = ei[e], ib = ei[e+1];
    int row = half ? ib : ia;
    uint2 u = hu[(size_t)row*32 + sl];
    float f0,f1,f2,f3;
    unpack2(u.x,f0,f1); unpack2(u.y,f2,f3);
    a0 += f0; a1 += f1; a2 += f2; a3 += f3;
  }
  if (e < end){
    uint2 u = hu[(size_t)ei[e]*32 + sl];
    if (!half){
      float f0,f1,f2,f3;
      unpack2(u.x,f0,f1); unpack2(u.y,f2,f3);
      a0 += f0; a1 += f1; a2 += f2; a3 += f3;
    }
  }
  a0 += __shfl_xor(a0, 32); a1 += __shfl_xor(a1, 32);
  a2 += __shfl_xor(a2, 32); a3 += __shfl_xor(a3, 32);
  const int d = end - beg;
  const float iv = 1.0f / (float)(d > 1 ? d : 1);
  if (!half){
    uint2 o; o.x = pack2(a0*iv, a1*iv); o.y = pack2(a2*iv, a3*iv);
    (blockIdx.y ? m1 : m0)[(size_t)node*32 + sl] = o;
  }
}

// ---- MFMA conv layer: 3-matrix bf16 GEMM (K=384) + bias + LN (+ReLU) ----
// Block 256 = 4 waves; wave w owns rows blk*64 + 16w .. +15, all 128 cols
// (8 col-tiles of 16). No LDS. A-frags from global bf16; B-frags from the
// pre-swizzled weight buffer (1KB coalesced per wave-load).
template<bool RELU, bool WF32, bool WB16>
__global__ void __launch_bounds__(256) k_conv(
    const ushort* __restrict__ h16, const ushort* __restrict__ m0,
    const ushort* __restrict__ m1, const ushort* __restrict__ Bsw,
    const float* __restrict__ bias, const float* __restrict__ gamma,
    const float* __restrict__ beta,
    float* __restrict__ outF, ushort* __restrict__ outB)
{
  const int t = threadIdx.x;
  const int wv = t >> 6, lane = t & 63;
  const int row0 = blockIdx.x*64 + wv*16;
  const int jc = lane & 15, g = lane >> 4;
  const int rA = row0 + jc;                 // A-operand row for this lane
  const bool okA = rA < NC;

  f32x4 acc[8];
  #pragma unroll
  for (int c = 0; c < 8; ++c) acc[c] = (f32x4){0.f,0.f,0.f,0.f};

  #pragma unroll
  for (int mat = 0; mat < 3; ++mat){
    const ushort* Abase = (mat == 0 ? h16 : (mat == 1 ? m0 : m1));
    const ushort* A = Abase + (size_t)rA*DD + g*8;
    #pragma unroll
    for (int tch = 0; tch < 4; ++tch){
      short8 af = (short8){0,0,0,0,0,0,0,0};
      if (okA) af = *(const short8*)(A + tch*32);
      const ushort* Bp = Bsw + ((mat*4 + tch)*8)*512 + lane*8;
      #pragma unroll
      for (int c = 0; c < 8; ++c){
        short8 bfr = *(const short8*)(Bp + c*512);
        acc[c] = __builtin_amdgcn_mfma_f32_16x16x32_bf16(af, bfr, acc[c], 0, 0, 0);
      }
    }
  }

  // epilogue: bias + LayerNorm (+ReLU). Row (g,r) lives in 16 lanes x 8 regs.
  float bs[8], gm[8], bt[8];
  #pragma unroll
  for (int c = 0; c < 8; ++c){
    bs[c] = bias[c*16 + jc]; gm[c] = gamma[c*16 + jc]; bt[c] = beta[c*16 + jc];
  }
  #pragma unroll
  for (int r = 0; r < 4; ++r){
    const int R = row0 + g*4 + r;           // D mapping: row = 4*(lane>>4)+reg
    float v[8]; float s = 0.f;
    #pragma unroll
    for (int c = 0; c < 8; ++c){ v[c] = acc[c][r] + bs[c]; s += v[c]; }
    s += __shfl_xor(s,1); s += __shfl_xor(s,2); s += __shfl_xor(s,4); s += __shfl_xor(s,8);
    float mu = s * (1.0f/128.0f);
    float q = 0.f;
    #pragma unroll
    for (int c = 0; c < 8; ++c){ float dd = v[c] - mu; q += dd*dd; }
    q += __shfl_xor(q,1); q += __shfl_xor(q,2); q += __shfl_xor(q,4); q += __shfl_xor(q,8);
    float rs = rsqrtf(q * (1.0f/128.0f) + 1e-5f);
    if (R < NC){
      #pragma unroll
      for (int c = 0; c < 8; ++c){
        float y = fmaf((v[c] - mu)*rs, gm[c], bt[c]);
        if (RELU) y = fmaxf(y, 0.f);
        if (WF32) outF[(size_t)R*DD + c*16 + jc] = y;
        if (WB16) outB[(size_t)R*DD + c*16 + jc] = __bfloat16_as_ushort(f2b(y));
      }
    }
  }
}

// ---- pc path: f32 VALU GEMM + bias + LN (+ReLU), 32 rows/block (small: 10k rows) ----
template<bool RELU>
__global__ void __launch_bounds__(256) k_pc(
    const float* __restrict__ A0, const float* __restrict__ W0,
    const float* __restrict__ bias, const float* __restrict__ gamma,
    const float* __restrict__ beta, float* __restrict__ out, int M)
{
  __shared__ float aS[DD][32];
  const int t = threadIdx.x;
  const int row0 = blockIdx.x * 32;
  const int wv = t >> 6, lane = t & 63;

  #pragma unroll
  for (int p = 0; p < 4; ++p){
    int f = t + p*256;
    int r = f >> 5, k4 = (f & 31) << 2;
    float4 v = make_float4(0.f,0.f,0.f,0.f);
    if (row0 + r < M) v = *(const float4*)(A0 + (size_t)(row0+r)*DD + k4);
    aS[k4+0][SWZ(k4+0,r)] = v.x; aS[k4+1][SWZ(k4+1,r)] = v.y;
    aS[k4+2][SWZ(k4+2,r)] = v.z; aS[k4+3][SWZ(k4+3,r)] = v.w;
  }
  __syncthreads();

  const int j0 = lane;
  const int r0 = wv << 3;
  float acc[8][2];
  #pragma unroll
  for (int r = 0; r < 8; ++r){ acc[r][0] = 0.f; acc[r][1] = 0.f; }

  #pragma unroll 2
  for (int k = 0; k < DD; ++k){
    const int rA = SWZ(k, r0), rB = SWZ(k, r0+4);
    float4 aA = *(const float4*)&aS[k][rA];
    float4 aB = *(const float4*)&aS[k][rB];
    float a[8] = {aA.x,aA.y,aA.z,aA.w,aB.x,aB.y,aB.z,aB.w};
    float w0 = W0[k*DD + j0], w1 = W0[k*DD + j0 + 64];
    #pragma unroll
    for (int r = 0; r < 8; ++r){
      acc[r][0] = fmaf(a[r], w0, acc[r][0]);
      acc[r][1] = fmaf(a[r], w1, acc[r][1]);
    }
  }

  float bj0 = bias[j0], bj1 = bias[j0+64];
  float g0 = gamma[j0], g1 = gamma[j0+64];
  float be0 = beta[j0], be1 = beta[j0+64];
  #pragma unroll
  for (int r = 0; r < 8; ++r){
    float v0 = acc[r][0] + bj0;
    float v1 = acc[r][1] + bj1;
    float s = v0 + v1;
    #pragma unroll
    for (int m = 32; m > 0; m >>= 1) s += __shfl_xor(s, m);
    float mu = s * (1.0f/128.0f);
    float d0 = v0 - mu, d1 = v1 - mu;
    float q = d0*d0 + d1*d1;
    #pragma unroll
    for (int m = 32; m > 0; m >>= 1) q += __shfl_xor(q, m);
    float rs = rsqrtf(q * (1.0f/128.0f) + 1e-5f);
    float y0 = fmaf(d0*rs, g0, be0);
    float y1 = fmaf(d1*rs, g1, be1);
    if (RELU){ y0 = fmaxf(y0, 0.f); y1 = fmaxf(y1, 0.f); }
    int row = row0 + r0 + r;
    if (row < M){
      out[(size_t)row*DD + j0]      = y0;
      out[(size_t)row*DD + j0 + 64] = y1;
    }
  }
}

extern "C" void kernel_launch(void* const* d_in, const int* in_sizes, int n_in,
                              void* d_out, int out_size, void* d_ws, size_t ws_size,
                              hipStream_t stream)
{
  const float* x_c    = (const float*)d_in[0];
  const float* x_pc   = (const float*)d_in[1];
  const int*   src0   = (const int*)d_in[2];
  const int*   dst0   = (const int*)d_in[3];
  const int*   src1   = (const int*)d_in[4];
  const int*   dst1   = (const int*)d_in[5];
  const float* W_self = (const float*)d_in[6];
  const float* W_nei  = (const float*)d_in[7];
  const float* b_nei  = (const float*)d_in[8];
  const float* lin_W  = (const float*)d_in[9];
  const float* lin_b  = (const float*)d_in[10];
  const float* ln_g   = (const float*)d_in[11];
  const float* ln_b   = (const float*)d_in[12];
  (void)in_sizes; (void)n_in; (void)out_size; (void)ws_size;

  char* ws = (char*)d_ws;
  size_t off = 0;
  auto take = [&](size_t bytes)->char*{
    char* p = ws + off; off += (bytes + 255) & ~(size_t)255; return p;
  };
  ushort* h16  = (ushort*)take((size_t)NC*DD*2);      // 25.6 MB (bf16 h, in-place per layer)
  uint2*  m0   = (uint2*) take((size_t)NC*DD*2);      // 25.6 MB bf16 means rel0
  uint2*  m1   = (uint2*) take((size_t)NC*DD*2);      // 25.6 MB bf16 means rel1
  ushort* Bsw  = (ushort*)take((size_t)NLAYER*WPL*2); //  0.3 MB swizzled bf16 weights
  float*  bsum = (float*) take((size_t)NLAYER*DD*4);
  int* rowptr0 = (int*)   take((size_t)(NC+1)*4);
  int* rowptr1 = (int*)   take((size_t)(NC+1)*4);
  int* cursor0 = (int*)   take((size_t)NC*4);
  int* cursor1 = (int*)   take((size_t)NC*4);
  int* eidx0   = (int*)   take((size_t)NE*4);         //  4.0 MB
  int* eidx1   = (int*)   take((size_t)NE*4);         //  4.0 MB
  int* part0   = (int*)   take(128*4);
  int* part1   = (int*)   take(128*4);                // total ~ 86 MB

  float* out_pc = (float*)d_out;                      // [NPC,128] f32, in-place pc chain
  float* out_h  = (float*)d_out + (size_t)NPC*DD;     // [NC,128]  f32, written once (layer 2)

  // prep: swizzled bf16 weights, folded biases, bf16 mirror of x_c
  k_prepw<<<(NLAYER*3*DSQ + 255)/256, 256, 0, stream>>>(W_self, W_nei, Bsw);
  k_prepb<<<(NLAYER*DD + 255)/256, 256, 0, stream>>>(b_nei, bsum);
  k_f2b<<<(NC*DD/8 + 255)/256, 256, 0, stream>>>(x_c, h16, NC*DD);

  // CSR build (graph is layer-invariant)
  hipMemsetAsync(cursor0, 0, (size_t)NC*4, stream);
  hipMemsetAsync(cursor1, 0, (size_t)NC*4, stream);
  k_count<<<dim3((NE + 255)/256, 2), 256, 0, stream>>>(dst0, dst1, cursor0, cursor1);
  const int SB = (NC + 1023)/1024;  // 98
  k_scan1<<<SB, 1024, 0, stream>>>(cursor0, rowptr0, part0);
  k_scan1<<<SB, 1024, 0, stream>>>(cursor1, rowptr1, part1);
  k_scan2<<<1, 128, 0, stream>>>(part0, SB);
  k_scan2<<<1, 128, 0, stream>>>(part1, SB);
  k_finalize<<<(NC + 255)/256, 256, 0, stream>>>(rowptr0, part0, cursor0);
  k_finalize<<<(NC + 255)/256, 256, 0, stream>>>(rowptr1, part1, cursor1);
  k_fill<<<dim3((NE + 255)/256, 2), 256, 0, stream>>>(src0, dst0, src1, dst1,
                                                      cursor0, cursor1, eidx0, eidx1);

  const dim3 AG(NC/4, 2);
  const int CB = (NC + 63)/64;     // 1563
  const int PB = (NPC + 31)/32;    // 313

  // layer 0
  k_agg<<<AG, 256, 0, stream>>>(h16, rowptr0, eidx0, rowptr1, eidx1, m0, m1);
  k_conv<true,false,true><<<CB, 256, 0, stream>>>(
      h16, (const ushort*)m0, (const ushort*)m1, Bsw,
      bsum, ln_g, ln_b, nullptr, h16);
  k_pc<true><<<PB, 256, 0, stream>>>(x_pc, lin_W, lin_b, ln_g, ln_b, out_pc, NPC);

  // layer 1
  k_agg<<<AG, 256, 0, stream>>>(h16, rowptr0, eidx0, rowptr1, eidx1, m0, m1);
  k_conv<true,false,true><<<CB, 256, 0, stream>>>(
      h16, (const ushort*)m0, (const ushort*)m1, Bsw + WPL,
      bsum + DD, ln_g + DD, ln_b + DD, nullptr, h16);
  k_pc<true><<<PB, 256, 0, stream>>>(out_pc, lin_W + DSQ, lin_b + DD,
                                     ln_g + DD, ln_b + DD, out_pc, NPC);

  // layer 2 (final: f32 out, no ReLU)
  k_agg<<<AG, 256, 0, stream>>>(h16, rowptr0, eidx0, rowptr1, eidx1, m0, m1);
  k_conv<false,true,false><<<CB, 256, 0, stream>>>(
      h16, (const ushort*)m0, (const ushort*)m1, Bsw + 2*WPL,
      bsum + 2*DD, ln_g + 2*DD, ln_b + 2*DD, out_h, nullptr);
  k_pc<false><<<PB, 256, 0, stream>>>(out_pc, lin_W + 2*DSQ, lin_b + 2*DD,
                                      ln_g + 2*DD, ln_b + 2*DD, out_pc, NPC);
}